// Round 9
// baseline (387.737 us; speedup 1.0000x reference)
//
#include <hip/hip_runtime.h>
#include <math.h>

#define Cc     8
#define FIELD  7
#define PAD    3
#define TW     32        // tile width
#define TH     16        // tile height
#define HAW    38        // TW + 6
#define HAH    22        // TH + 6
#define QSTR   39        // qs row stride (uint4); col 38 = pad col (staged, zero weight)
#define NSTG   (HAH*QSTR)  // 858 staged uint4 per tile
#define BB     32
#define HH     384
#define WW     384
#define NB     4         // batches per block (software-pipelined)
#define NSLOT  64        // 8 dy' x 8 dx slots (dx==7 zero-pad) for a row-PAIR
#define UCLIP  13.815510557964274f   // -log(1e-6)

typedef __attribute__((ext_vector_type(8))) short short8;  // 8 bf16 = 4 VGPRs
typedef __attribute__((ext_vector_type(4))) float f32x4;   // MFMA C/D

__device__ __forceinline__ unsigned short f2bf(float f) {   // RNE fp32->bf16
    unsigned u = __float_as_uint(f);
    u += 0x7FFFu + ((u >> 16) & 1u);
    return (unsigned short)(u >> 16);
}
__device__ __forceinline__ unsigned short f2h(float f) {    // RNE fp32->fp16
    return __builtin_bit_cast(unsigned short, (_Float16)f);
}
__device__ __forceinline__ float hlo(unsigned u) {
    return (float)__builtin_bit_cast(_Float16, (unsigned short)(u & 0xFFFFu));
}
__device__ __forceinline__ float hhi(unsigned u) {
    return (float)__builtin_bit_cast(_Float16, (unsigned short)(u >> 16));
}

// q = bf16-packed softmax(xv); if inter, vp = fp16-packed (b - u@W), u=min(lse-x,UCLIP)
__device__ __forceinline__ void px_qv(const float xv[Cc],
                                      const float* __restrict__ sw,
                                      const float* __restrict__ sb,
                                      bool inter, uint4& qp, uint4& vp) {
    float m = xv[0];
#pragma unroll
    for (int c = 1; c < Cc; ++c) m = fmaxf(m, xv[c]);
    float s = 0.f, e[Cc];
#pragma unroll
    for (int c = 0; c < Cc; ++c) { e[c] = __expf(xv[c] - m); s += e[c]; }
    float inv = 1.f / s;
    qp.x = f2bf(e[0] * inv) | ((unsigned)f2bf(e[1] * inv) << 16);
    qp.y = f2bf(e[2] * inv) | ((unsigned)f2bf(e[3] * inv) << 16);
    qp.z = f2bf(e[4] * inv) | ((unsigned)f2bf(e[5] * inv) << 16);
    qp.w = f2bf(e[6] * inv) | ((unsigned)f2bf(e[7] * inv) << 16);
    if (inter) {
        float lse = m + __logf(s);
        float u[Cc];
#pragma unroll
        for (int c = 0; c < Cc; ++c) u[c] = fminf(lse - xv[c], UCLIP);
        float vv[Cc];
#pragma unroll
        for (int d = 0; d < Cc; ++d) {
            float a = sb[d];
#pragma unroll
            for (int c = 0; c < Cc; ++c) a = fmaf(-u[c], sw[c * Cc + d], a);
            vv[d] = a;
        }
        vp.x = f2h(vv[0]) | ((unsigned)f2h(vv[1]) << 16);
        vp.y = f2h(vv[2]) | ((unsigned)f2h(vv[3]) << 16);
        vp.z = f2h(vv[4]) | ((unsigned)f2h(vv[5]) << 16);
        vp.w = f2h(vv[6]) | ((unsigned)f2h(vv[7]) << 16);
    }
}

// ---------------------------------------------------------------------------
// prep_w: row-pair fused weight table, dx-major slot layout (R6/R7-verified).
// ---------------------------------------------------------------------------
__global__ __launch_bounds__(256)
void prep_w(const float* __restrict__ kw, const float* __restrict__ sw,
            unsigned short* __restrict__ wtab) {
    int it = blockIdx.x * 256 + threadIdx.x;      // (slot, j=cin)
    if (it >= NSLOT * 8) return;
    int s = it >> 3, j = it & 7;
    int dyp = s >> 3, dx = s & 7;
#pragma unroll
    for (int n = 0; n < 16; ++n) {
        int h = n >> 3, d = n & 7;
        int dy = dyp - h;
        float a = 0.f;
        if (dy >= 0 && dy < FIELD && dx < 7) {
            int tap = dy * 7 + dx;
#pragma unroll
            for (int c = 0; c < Cc; ++c) {
                float kv = (c == j) ? 0.f : kw[(tap * Cc + j) * Cc + c];
                a = fmaf(kv, sw[c * Cc + d], a);
            }
        }
        wtab[(s * 16 + n) * 8 + j] = f2bf(a);
    }
}

// ---------------------------------------------------------------------------
// init_qv (FALLBACK path only): q0 = softmax(x) bf16x8; v fp32 in vf.
// ---------------------------------------------------------------------------
__global__ __launch_bounds__(256)
void init_qv(const float* __restrict__ x, const float* __restrict__ sw,
             const float* __restrict__ sb,
             uint4* __restrict__ q0, float* __restrict__ vf) {
    long long p = (long long)blockIdx.x * 256 + threadIdx.x;
    const float4* xp = (const float4*)(x + p * Cc);
    float4 a0 = xp[0], a1 = xp[1];
    float xv[Cc] = {a0.x, a0.y, a0.z, a0.w, a1.x, a1.y, a1.z, a1.w};
    float m = xv[0];
#pragma unroll
    for (int c = 1; c < Cc; ++c) m = fmaxf(m, xv[c]);
    float s = 0.f, e[Cc];
#pragma unroll
    for (int c = 0; c < Cc; ++c) { e[c] = __expf(xv[c] - m); s += e[c]; }
    float inv = 1.f / s;
    uint4 qo;
    qo.x = f2bf(e[0] * inv) | ((unsigned)f2bf(e[1] * inv) << 16);
    qo.y = f2bf(e[2] * inv) | ((unsigned)f2bf(e[3] * inv) << 16);
    qo.z = f2bf(e[4] * inv) | ((unsigned)f2bf(e[5] * inv) << 16);
    qo.w = f2bf(e[6] * inv) | ((unsigned)f2bf(e[7] * inv) << 16);
    q0[p] = qo;

    float lse = m + __logf(s);
    float u[Cc];
#pragma unroll
    for (int c = 0; c < Cc; ++c) u[c] = fminf(lse - xv[c], UCLIP);
    float vv[Cc];
#pragma unroll
    for (int d = 0; d < Cc; ++d) {
        float a = sb[d];
#pragma unroll
        for (int c = 0; c < Cc; ++c) a = fmaf(-u[c], sw[c * Cc + d], a);
        vv[d] = a;
    }
    float4* vp = (float4*)(vf + p * Cc);
    vp[0] = make_float4(vv[0], vv[1], vv[2], vv[3]);
    vp[1] = make_float4(vv[4], vv[5], vv[6], vv[7]);
}

// ---------------------------------------------------------------------------
// mrf_first: FUSED init + iteration 1.
// Stages x (fp32) per halo pixel, computes softmax(x) -> bf16 q-tile in LDS
// (bit-identical to init_qv->stage), computes v for interior pixels -> global
// vh (fp16, for iters 2-5) + LDS vs (for this kernel's epilogue). Then the
// R7-verified conv/epilogue. Deletes the init_qv pass (q0 write+read, 151 MB).
// ---------------------------------------------------------------------------
__global__ __launch_bounds__(512)
void mrf_first(const float* __restrict__ x,
               const unsigned short* __restrict__ wtab,
               const float* __restrict__ sw, const float* __restrict__ sb,
               uint4* __restrict__ vh,          // out: v fp16x8 per pixel
               uint4* __restrict__ qout) {      // out: q1 bf16x8 per pixel
    __shared__ __align__(16) uint4 qs[2][NSTG];       // 2 x 13728 B
    __shared__ __align__(16) uint4 vs[2][TH * TW];    // 2 x 8192 B

    const int tid = threadIdx.x;
    const int wv  = tid >> 6;
    const int l   = tid & 63;
    const int m   = l & 15;
    const int g   = l >> 4;

    const int w0 = blockIdx.x * TW;
    const int h0 = blockIdx.y * TH;
    const int b0 = blockIdx.z * NB;

    const int r0 = 4 * (wv >> 1);
    const int cx = 16 * (wv & 1);

    const int p   = g & 1;
    const int row = r0 + 2 * p + (g >> 1);
    const int px  = cx + m;
    const long long pixoff = (long long)(h0 + row) * WW + (w0 + px);
    const long long BSTR   = (long long)HH * WW;

    // --- A fragments (weights): once per block ---
    short8 bw[8][2];
#pragma unroll
    for (int dyq = 0; dyq < 8; ++dyq)
#pragma unroll
        for (int dxb = 0; dxb < 2; ++dxb) {
            int s = dyq * 8 + 4 * dxb + g;
            uint4 t = *(const uint4*)(wtab + (s * 16 + m) * 8);
            bw[dyq][dxb] = __builtin_bit_cast(short8, t);
        }

    // --- staging geometry (batch-independent) ---
    const int sy0 = tid / QSTR, sx0 = tid - sy0 * QSTR;
    const int gh0 = h0 + sy0 - PAD, gw0 = w0 + sx0 - PAD;
    const bool in0 = (gh0 >= 0 && gh0 < HH && gw0 >= 0 && gw0 < WW);
    const bool it0 = (sy0 >= PAD && sy0 < PAD + TH && sx0 >= PAD && sx0 < PAD + TW);
    const int  vi0 = (sy0 - PAD) * TW + (sx0 - PAD);
    const long long off0 = (long long)gh0 * WW + gw0;
    const int  s1  = tid + 512;
    const bool has1 = (s1 < NSTG);
    const int sy1 = s1 / QSTR, sx1 = s1 - sy1 * QSTR;
    const int gh1 = h0 + sy1 - PAD, gw1 = w0 + sx1 - PAD;
    const bool in1 = has1 && (gh1 >= 0 && gh1 < HH && gw1 >= 0 && gw1 < WW);
    const bool it1 = has1 && (sy1 >= PAD && sy1 < PAD + TH && sx1 >= PAD && sx1 < PAD + TW);
    const int  vi1 = (sy1 - PAD) * TW + (sx1 - PAD);
    const long long off1 = (long long)gh1 * WW + gw1;

    const float4* xb = (const float4*)x;   // 2 float4 per pixel
    const uint4   zz = make_uint4(0, 0, 0, 0);

    // --- prologue: stage tile 0 (softmax + v) ---
    {
        float xa[Cc] = {0,0,0,0,0,0,0,0};
        if (in0) {
            float4 t0 = xb[(b0 * BSTR + off0) * 2], t1 = xb[(b0 * BSTR + off0) * 2 + 1];
            xa[0]=t0.x; xa[1]=t0.y; xa[2]=t0.z; xa[3]=t0.w;
            xa[4]=t1.x; xa[5]=t1.y; xa[6]=t1.z; xa[7]=t1.w;
        }
        uint4 qp = zz, vp = zz;
        if (in0) px_qv(xa, sw, sb, it0, qp, vp);
        qs[0][tid] = qp;
        if (it0) { vh[b0 * BSTR + off0] = vp; vs[0][vi0] = vp; }
        if (has1) {
            float xc[Cc] = {0,0,0,0,0,0,0,0};
            if (in1) {
                float4 t0 = xb[(b0 * BSTR + off1) * 2], t1 = xb[(b0 * BSTR + off1) * 2 + 1];
                xc[0]=t0.x; xc[1]=t0.y; xc[2]=t0.z; xc[3]=t0.w;
                xc[4]=t1.x; xc[5]=t1.y; xc[6]=t1.z; xc[7]=t1.w;
            }
            uint4 qp1 = zz, vp1 = zz;
            if (in1) px_qv(xc, sw, sb, it1, qp1, vp1);
            qs[0][s1] = qp1;
            if (it1) { vh[b0 * BSTR + off1] = vp1; vs[0][vi1] = vp1; }
        }
    }
    __syncthreads();

#pragma unroll
    for (int t = 0; t < NB; ++t) {
        // --- prefetch x(t+1) into registers ---
        float4 n0a = make_float4(0,0,0,0), n0b = n0a, n1a = n0a, n1b = n0a;
        if (t + 1 < NB) {
            const long long bo = (long long)(b0 + t + 1) * BSTR;
            if (in0) { n0a = xb[(bo + off0) * 2]; n0b = xb[(bo + off0) * 2 + 1]; }
            if (in1) { n1a = xb[(bo + off1) * 2]; n1b = xb[(bo + off1) * 2 + 1]; }
        }

        // --- K loop on qs[t&1] ---
        f32x4 acc0 = (f32x4){0.f, 0.f, 0.f, 0.f};
        f32x4 acc1 = (f32x4){0.f, 0.f, 0.f, 0.f};
        const uint4* Q = qs[t & 1];
        const int colbase = cx + m + g;
#pragma unroll
        for (int dyp = 0; dyp < 10; ++dyp) {
            const int rb = (r0 + dyp) * QSTR + colbase;
#pragma unroll
            for (int dxb = 0; dxb < 2; ++dxb) {
                short8 qv = *(const short8*)&Q[rb + 4 * dxb];
                if (dyp < 8)
                    acc0 = __builtin_amdgcn_mfma_f32_16x16x32_bf16(bw[dyp][dxb], qv, acc0, 0, 0, 0);
                if (dyp >= 2)
                    acc1 = __builtin_amdgcn_mfma_f32_16x16x32_bf16(bw[dyp - 2][dxb], qv, acc1, 0, 0, 0);
            }
        }

        // --- in-register transpose ---
        float o[Cc];
#pragma unroll
        for (int tt = 0; tt < 4; ++tt) {
            float s0v = __shfl_xor(acc0[tt], 16);
            float s1v = __shfl_xor(acc1[tt], 16);
            o[tt]     = p ? s1v      : acc0[tt];
            o[4 + tt] = p ? acc1[tt] : s0v;
        }

        // --- epilogue: v from LDS, softmax, write q1 ---
        {
            uint4 vhv = vs[t & 1][row * TW + px];
            float vv[Cc] = {hlo(vhv.x), hhi(vhv.x), hlo(vhv.y), hhi(vhv.y),
                            hlo(vhv.z), hhi(vhv.z), hlo(vhv.w), hhi(vhv.w)};
#pragma unroll
            for (int d = 0; d < Cc; ++d) o[d] = vv[d] - o[d];
            float mm = o[0];
#pragma unroll
            for (int d = 1; d < Cc; ++d) mm = fmaxf(mm, o[d]);
            float ss = 0.f, e[Cc];
#pragma unroll
            for (int d = 0; d < Cc; ++d) { e[d] = __expf(o[d] - mm); ss += e[d]; }
            float inv = 1.f / ss;
            uint4 qo;
            qo.x = f2bf(e[0] * inv) | ((unsigned)f2bf(e[1] * inv) << 16);
            qo.y = f2bf(e[2] * inv) | ((unsigned)f2bf(e[3] * inv) << 16);
            qo.z = f2bf(e[4] * inv) | ((unsigned)f2bf(e[5] * inv) << 16);
            qo.w = f2bf(e[6] * inv) | ((unsigned)f2bf(e[7] * inv) << 16);
            qout[(b0 + t) * BSTR + pixoff] = qo;
        }

        // --- commit tile t+1: softmax + v from prefetched x ---
        if (t + 1 < NB) {
            const int nb = (t + 1) & 1;
            const long long bo = (long long)(b0 + t + 1) * BSTR;
            float xa[Cc] = {n0a.x, n0a.y, n0a.z, n0a.w, n0b.x, n0b.y, n0b.z, n0b.w};
            uint4 qp = zz, vp = zz;
            if (in0) px_qv(xa, sw, sb, it0, qp, vp);
            qs[nb][tid] = qp;
            if (it0) { vh[bo + off0] = vp; vs[nb][vi0] = vp; }
            if (has1) {
                float xc[Cc] = {n1a.x, n1a.y, n1a.z, n1a.w, n1b.x, n1b.y, n1b.z, n1b.w};
                uint4 qp1 = zz, vp1 = zz;
                if (in1) px_qv(xc, sw, sb, it1, qp1, vp1);
                qs[nb][s1] = qp1;
                if (it1) { vh[bo + off1] = vp1; vs[nb][vi1] = vp1; }
            }
            __syncthreads();
        }
    }
}

// ---------------------------------------------------------------------------
// mrf_iter: R7/R8-verified iteration kernel (VHALF: v fp16 vs fp32).
// ---------------------------------------------------------------------------
template<int VHALF>
__global__ __launch_bounds__(512)
void mrf_iter(const uint4* __restrict__ qin,
              const unsigned short* __restrict__ wtab,
              const void* __restrict__ vsrc,
              uint4* __restrict__ qout,
              float* __restrict__ lout,
              int last) {
    __shared__ __align__(16) uint4 qs[2][NSTG];

    const int tid = threadIdx.x;
    const int wv  = tid >> 6;
    const int l   = tid & 63;
    const int m   = l & 15;
    const int g   = l >> 4;

    const int w0 = blockIdx.x * TW;
    const int h0 = blockIdx.y * TH;
    const int b0 = blockIdx.z * NB;

    const int r0 = 4 * (wv >> 1);
    const int cx = 16 * (wv & 1);

    const int p   = g & 1;
    const int row = r0 + 2 * p + (g >> 1);
    const int px  = cx + m;
    const long long pixoff = (long long)(h0 + row) * WW + (w0 + px);
    const long long BSTR   = (long long)HH * WW;

    short8 bw[8][2];
#pragma unroll
    for (int dyq = 0; dyq < 8; ++dyq)
#pragma unroll
        for (int dxb = 0; dxb < 2; ++dxb) {
            int s = dyq * 8 + 4 * dxb + g;
            uint4 t = *(const uint4*)(wtab + (s * 16 + m) * 8);
            bw[dyq][dxb] = __builtin_bit_cast(short8, t);
        }

    const int sy0 = tid / QSTR, sx0 = tid - sy0 * QSTR;
    const int gh0 = h0 + sy0 - PAD, gw0 = w0 + sx0 - PAD;
    const bool in0 = (gh0 >= 0 && gh0 < HH && gw0 >= 0 && gw0 < WW);
    const long long off0 = (long long)gh0 * WW + gw0;
    const int  s1  = tid + 512;
    const bool has1 = (s1 < NSTG);
    const int sy1 = s1 / QSTR, sx1 = s1 - sy1 * QSTR;
    const int gh1 = h0 + sy1 - PAD, gw1 = w0 + sx1 - PAD;
    const bool in1 = has1 && (gh1 >= 0 && gh1 < HH && gw1 >= 0 && gw1 < WW);
    const long long off1 = (long long)gh1 * WW + gw1;

    const uint4* qb = qin + b0 * BSTR;
    const uint4  zz = make_uint4(0, 0, 0, 0);

    uint4 c0 = in0 ? qb[off0] : zz;
    uint4 c1 = in1 ? qb[off1] : zz;
    uint4  vhv = zz;
    float4 v0, v1;
    if constexpr (VHALF) {
        vhv = ((const uint4*)vsrc)[b0 * BSTR + pixoff];
    } else {
        const float4* vp0 = (const float4*)((const float*)vsrc + (b0 * BSTR + pixoff) * Cc);
        v0 = vp0[0]; v1 = vp0[1];
    }
    qs[0][tid] = c0;
    if (has1) qs[0][s1] = c1;
    __syncthreads();

#pragma unroll
    for (int t = 0; t < NB; ++t) {
        uint4 n0 = zz, n1 = zz, vhn = zz;
        float4 vn0 = make_float4(0.f, 0.f, 0.f, 0.f), vn1 = vn0;
        if (t + 1 < NB) {
            const uint4* qbn = qb + (t + 1) * BSTR;
            n0 = in0 ? qbn[off0] : zz;
            n1 = in1 ? qbn[off1] : zz;
            if constexpr (VHALF) {
                vhn = ((const uint4*)vsrc)[(b0 + t + 1) * BSTR + pixoff];
            } else {
                const float4* vpn = (const float4*)((const float*)vsrc + ((b0 + t + 1) * BSTR + pixoff) * Cc);
                vn0 = vpn[0]; vn1 = vpn[1];
            }
        }

        f32x4 acc0 = (f32x4){0.f, 0.f, 0.f, 0.f};
        f32x4 acc1 = (f32x4){0.f, 0.f, 0.f, 0.f};
        const uint4* Q = qs[t & 1];
        const int colbase = cx + m + g;
#pragma unroll
        for (int dyp = 0; dyp < 10; ++dyp) {
            const int rb = (r0 + dyp) * QSTR + colbase;
#pragma unroll
            for (int dxb = 0; dxb < 2; ++dxb) {
                short8 qv = *(const short8*)&Q[rb + 4 * dxb];
                if (dyp < 8)
                    acc0 = __builtin_amdgcn_mfma_f32_16x16x32_bf16(bw[dyp][dxb], qv, acc0, 0, 0, 0);
                if (dyp >= 2)
                    acc1 = __builtin_amdgcn_mfma_f32_16x16x32_bf16(bw[dyp - 2][dxb], qv, acc1, 0, 0, 0);
            }
        }

        float o[Cc];
#pragma unroll
        for (int tt = 0; tt < 4; ++tt) {
            float s0v = __shfl_xor(acc0[tt], 16);
            float s1v = __shfl_xor(acc1[tt], 16);
            o[tt]     = p ? s1v      : acc0[tt];
            o[4 + tt] = p ? acc1[tt] : s0v;
        }

        float vv[Cc];
        if constexpr (VHALF) {
            vv[0] = hlo(vhv.x); vv[1] = hhi(vhv.x);
            vv[2] = hlo(vhv.y); vv[3] = hhi(vhv.y);
            vv[4] = hlo(vhv.z); vv[5] = hhi(vhv.z);
            vv[6] = hlo(vhv.w); vv[7] = hhi(vhv.w);
        } else {
            vv[0] = v0.x; vv[1] = v0.y; vv[2] = v0.z; vv[3] = v0.w;
            vv[4] = v1.x; vv[5] = v1.y; vv[6] = v1.z; vv[7] = v1.w;
        }
#pragma unroll
        for (int d = 0; d < Cc; ++d) o[d] = vv[d] - o[d];
        const long long pix = (b0 + t) * BSTR + pixoff;
        if (last) {
            float4* op = (float4*)(lout + pix * Cc);
            op[0] = make_float4(o[0], o[1], o[2], o[3]);
            op[1] = make_float4(o[4], o[5], o[6], o[7]);
        } else {
            float mm = o[0];
#pragma unroll
            for (int d = 1; d < Cc; ++d) mm = fmaxf(mm, o[d]);
            float ss = 0.f, e[Cc];
#pragma unroll
            for (int d = 0; d < Cc; ++d) { e[d] = __expf(o[d] - mm); ss += e[d]; }
            float inv = 1.f / ss;
            uint4 qo;
            qo.x = f2bf(e[0] * inv) | ((unsigned)f2bf(e[1] * inv) << 16);
            qo.y = f2bf(e[2] * inv) | ((unsigned)f2bf(e[3] * inv) << 16);
            qo.z = f2bf(e[4] * inv) | ((unsigned)f2bf(e[5] * inv) << 16);
            qo.w = f2bf(e[6] * inv) | ((unsigned)f2bf(e[7] * inv) << 16);
            qout[pix] = qo;
        }

        if (t + 1 < NB) {
            qs[(t + 1) & 1][tid] = n0;
            if (has1) qs[(t + 1) & 1][s1] = n1;
            __syncthreads();
            if constexpr (VHALF) { vhv = vhn; } else { v0 = vn0; v1 = vn1; }
        }
    }
}

extern "C" void kernel_launch(void* const* d_in, const int* in_sizes, int n_in,
                              void* d_out, int out_size, void* d_ws, size_t ws_size,
                              hipStream_t stream) {
    (void)in_sizes; (void)n_in; (void)out_size;
    const float* x  = (const float*)d_in[0];   // [32,384,384,8]
    const float* kw = (const float*)d_in[1];   // [7,7,8,8]
    const float* sw = (const float*)d_in[2];   // [8,8]
    const float* sb = (const float*)d_in[3];   // [8]

    const size_t QSZ = (size_t)BB * HH * WW * 16;   // 75,497,472 B (bf16x8)
    const size_t VSZ = (size_t)BB * HH * WW * 16;   // 75,497,472 B (fp16x8)
    uint4* qA = (uint4*)d_ws;
    uint4* qB = (uint4*)((char*)d_ws + QSZ);

    const long long npix = (long long)BB * HH * WW;
    dim3 grid(WW / TW, HH / TH, BB / NB);   // 12 x 24 x 8

    if (ws_size >= 2 * QSZ + VSZ + 16384) {
        // fp16-v path with fused first iteration
        uint4* vh = (uint4*)((char*)d_ws + 2 * QSZ);
        unsigned short* wt = (unsigned short*)((char*)d_ws + 2 * QSZ + VSZ);
        prep_w<<<2, 256, 0, stream>>>(kw, sw, wt);
        mrf_first<<<grid, 512, 0, stream>>>(x, wt, sw, sb, vh, qB);
        mrf_iter<1><<<grid, 512, 0, stream>>>(qB, wt, vh, qA, nullptr, 0);
        mrf_iter<1><<<grid, 512, 0, stream>>>(qA, wt, vh, qB, nullptr, 0);
        mrf_iter<1><<<grid, 512, 0, stream>>>(qB, wt, vh, qA, nullptr, 0);
        mrf_iter<1><<<grid, 512, 0, stream>>>(qA, wt, vh, nullptr, (float*)d_out, 1);
    } else {
        // fallback: exact R7-verified fp32-v-in-d_out path
        float* vbuf = (float*)d_out;
        unsigned short* wt = (unsigned short*)((char*)d_ws + 2 * QSZ);
        prep_w<<<2, 256, 0, stream>>>(kw, sw, wt);
        init_qv<<<(int)(npix / 256), 256, 0, stream>>>(x, sw, sb, qA, vbuf);
        mrf_iter<0><<<grid, 512, 0, stream>>>(qA, wt, vbuf, qB, nullptr, 0);
        mrf_iter<0><<<grid, 512, 0, stream>>>(qB, wt, vbuf, qA, nullptr, 0);
        mrf_iter<0><<<grid, 512, 0, stream>>>(qA, wt, vbuf, qB, nullptr, 0);
        mrf_iter<0><<<grid, 512, 0, stream>>>(qB, wt, vbuf, qA, nullptr, 0);
        mrf_iter<0><<<grid, 512, 0, stream>>>(qA, wt, vbuf, nullptr, (float*)d_out, 1);
    }
}

// Round 10
// 381.629 us; speedup vs baseline: 1.0160x; 1.0160x over previous
//
#include <hip/hip_runtime.h>
#include <math.h>

#define Cc     8
#define FIELD  7
#define PAD    3
#define TW     32        // tile width
#define TH     16        // tile height
#define HAW    38        // TW + 6
#define HAH    22        // TH + 6
#define QSTR   39        // qs row stride (uint4); col 38 = pad col (staged, zero weight)
#define NSTG   (HAH*QSTR)  // 858 staged uint4 per tile
#define BB     32
#define HH     384
#define WW     384
#define NB     4         // batches per block in mrf_iter (software-pipelined)
#define NSLOT  64        // 8 dy' x 8 dx slots (dx==7 zero-pad) for a row-PAIR
#define UCLIP  13.815510557964274f   // -log(1e-6)

typedef __attribute__((ext_vector_type(8))) short short8;  // 8 bf16 = 4 VGPRs
typedef __attribute__((ext_vector_type(4))) float f32x4;   // MFMA C/D

__device__ __forceinline__ unsigned short f2bf(float f) {   // RNE fp32->bf16
    unsigned u = __float_as_uint(f);
    u += 0x7FFFu + ((u >> 16) & 1u);
    return (unsigned short)(u >> 16);
}
__device__ __forceinline__ unsigned short f2h(float f) {    // RNE fp32->fp16
    return __builtin_bit_cast(unsigned short, (_Float16)f);
}
__device__ __forceinline__ float hlo(unsigned u) {
    return (float)__builtin_bit_cast(_Float16, (unsigned short)(u & 0xFFFFu));
}
__device__ __forceinline__ float hhi(unsigned u) {
    return (float)__builtin_bit_cast(_Float16, (unsigned short)(u >> 16));
}

// q = bf16-packed softmax(xv); if inter, vp = fp16-packed (b - u@W), u=min(lse-x,UCLIP)
__device__ __forceinline__ void px_qv(const float xv[Cc],
                                      const float* __restrict__ sw,
                                      const float* __restrict__ sb,
                                      bool inter, uint4& qp, uint4& vp) {
    float m = xv[0];
#pragma unroll
    for (int c = 1; c < Cc; ++c) m = fmaxf(m, xv[c]);
    float s = 0.f, e[Cc];
#pragma unroll
    for (int c = 0; c < Cc; ++c) { e[c] = __expf(xv[c] - m); s += e[c]; }
    float inv = 1.f / s;
    qp.x = f2bf(e[0] * inv) | ((unsigned)f2bf(e[1] * inv) << 16);
    qp.y = f2bf(e[2] * inv) | ((unsigned)f2bf(e[3] * inv) << 16);
    qp.z = f2bf(e[4] * inv) | ((unsigned)f2bf(e[5] * inv) << 16);
    qp.w = f2bf(e[6] * inv) | ((unsigned)f2bf(e[7] * inv) << 16);
    if (inter) {
        float lse = m + __logf(s);
        float u[Cc];
#pragma unroll
        for (int c = 0; c < Cc; ++c) u[c] = fminf(lse - xv[c], UCLIP);
        float vv[Cc];
#pragma unroll
        for (int d = 0; d < Cc; ++d) {
            float a = sb[d];
#pragma unroll
            for (int c = 0; c < Cc; ++c) a = fmaf(-u[c], sw[c * Cc + d], a);
            vv[d] = a;
        }
        vp.x = f2h(vv[0]) | ((unsigned)f2h(vv[1]) << 16);
        vp.y = f2h(vv[2]) | ((unsigned)f2h(vv[3]) << 16);
        vp.z = f2h(vv[4]) | ((unsigned)f2h(vv[5]) << 16);
        vp.w = f2h(vv[6]) | ((unsigned)f2h(vv[7]) << 16);
    }
}

// ---------------------------------------------------------------------------
// prep_w: row-pair fused weight table, dx-major slot layout (R6/R7-verified).
// ---------------------------------------------------------------------------
__global__ __launch_bounds__(256)
void prep_w(const float* __restrict__ kw, const float* __restrict__ sw,
            unsigned short* __restrict__ wtab) {
    int it = blockIdx.x * 256 + threadIdx.x;      // (slot, j=cin)
    if (it >= NSLOT * 8) return;
    int s = it >> 3, j = it & 7;
    int dyp = s >> 3, dx = s & 7;
#pragma unroll
    for (int n = 0; n < 16; ++n) {
        int h = n >> 3, d = n & 7;
        int dy = dyp - h;
        float a = 0.f;
        if (dy >= 0 && dy < FIELD && dx < 7) {
            int tap = dy * 7 + dx;
#pragma unroll
            for (int c = 0; c < Cc; ++c) {
                float kv = (c == j) ? 0.f : kw[(tap * Cc + j) * Cc + c];
                a = fmaf(kv, sw[c * Cc + d], a);
            }
        }
        wtab[(s * 16 + n) * 8 + j] = f2bf(a);
    }
}

// ---------------------------------------------------------------------------
// init_qv (FALLBACK path only): q0 = softmax(x) bf16x8; v fp32 in vf.
// ---------------------------------------------------------------------------
__global__ __launch_bounds__(256)
void init_qv(const float* __restrict__ x, const float* __restrict__ sw,
             const float* __restrict__ sb,
             uint4* __restrict__ q0, float* __restrict__ vf) {
    long long p = (long long)blockIdx.x * 256 + threadIdx.x;
    const float4* xp = (const float4*)(x + p * Cc);
    float4 a0 = xp[0], a1 = xp[1];
    float xv[Cc] = {a0.x, a0.y, a0.z, a0.w, a1.x, a1.y, a1.z, a1.w};
    float m = xv[0];
#pragma unroll
    for (int c = 1; c < Cc; ++c) m = fmaxf(m, xv[c]);
    float s = 0.f, e[Cc];
#pragma unroll
    for (int c = 0; c < Cc; ++c) { e[c] = __expf(xv[c] - m); s += e[c]; }
    float inv = 1.f / s;
    uint4 qo;
    qo.x = f2bf(e[0] * inv) | ((unsigned)f2bf(e[1] * inv) << 16);
    qo.y = f2bf(e[2] * inv) | ((unsigned)f2bf(e[3] * inv) << 16);
    qo.z = f2bf(e[4] * inv) | ((unsigned)f2bf(e[5] * inv) << 16);
    qo.w = f2bf(e[6] * inv) | ((unsigned)f2bf(e[7] * inv) << 16);
    q0[p] = qo;

    float lse = m + __logf(s);
    float u[Cc];
#pragma unroll
    for (int c = 0; c < Cc; ++c) u[c] = fminf(lse - xv[c], UCLIP);
    float vv[Cc];
#pragma unroll
    for (int d = 0; d < Cc; ++d) {
        float a = sb[d];
#pragma unroll
        for (int c = 0; c < Cc; ++c) a = fmaf(-u[c], sw[c * Cc + d], a);
        vv[d] = a;
    }
    float4* vp = (float4*)(vf + p * Cc);
    vp[0] = make_float4(vv[0], vv[1], vv[2], vv[3]);
    vp[1] = make_float4(vv[4], vv[5], vv[6], vv[7]);
}

// ---------------------------------------------------------------------------
// mrf_first: FUSED init + iteration 1, NB=1 (no batch pipeline).
// LDS = 13.7K qs + 8.2K vs = 21.9 KB -> 4 blocks/CU (wave-capped); 9216
// blocks give cross-block TLP to hide the px_qv VALU chains and x-load
// latency (R9's 44KB dbuf version collapsed occupancy to 22% for nothing).
// Math identical to the R9-passing kernel.
// ---------------------------------------------------------------------------
__global__ __launch_bounds__(512)
void mrf_first(const float* __restrict__ x,
               const unsigned short* __restrict__ wtab,
               const float* __restrict__ sw, const float* __restrict__ sb,
               uint4* __restrict__ vh,          // out: v fp16x8 per pixel
               uint4* __restrict__ qout) {      // out: q1 bf16x8 per pixel
    __shared__ __align__(16) uint4 qs[NSTG];          // 13728 B
    __shared__ __align__(16) uint4 vs[TH * TW];       // 8192 B

    const int tid = threadIdx.x;
    const int wv  = tid >> 6;
    const int l   = tid & 63;
    const int m   = l & 15;
    const int g   = l >> 4;

    const int w0 = blockIdx.x * TW;
    const int h0 = blockIdx.y * TH;
    const int b  = blockIdx.z;

    const int r0 = 4 * (wv >> 1);
    const int cx = 16 * (wv & 1);

    const int p   = g & 1;
    const int row = r0 + 2 * p + (g >> 1);
    const int px  = cx + m;
    const long long BSTR = (long long)HH * WW;
    const long long pix  = (long long)b * BSTR + (long long)(h0 + row) * WW + (w0 + px);

    // --- A fragments (weights) ---
    short8 bw[8][2];
#pragma unroll
    for (int dyq = 0; dyq < 8; ++dyq)
#pragma unroll
        for (int dxb = 0; dxb < 2; ++dxb) {
            int s = dyq * 8 + 4 * dxb + g;
            uint4 t = *(const uint4*)(wtab + (s * 16 + m) * 8);
            bw[dyq][dxb] = __builtin_bit_cast(short8, t);
        }

    // --- staging: 1-2 slots per thread; softmax(x) -> qs, v -> vh + vs ---
    const float4* xb = (const float4*)x;   // 2 float4 per pixel
    const uint4   zz = make_uint4(0, 0, 0, 0);
#pragma unroll
    for (int ss = 0; ss < 2; ++ss) {
        const int s = tid + ss * 512;
        if (s >= NSTG) break;
        const int sy = s / QSTR, sx = s - sy * QSTR;
        const int gh = h0 + sy - PAD, gw = w0 + sx - PAD;
        const bool in = (gh >= 0 && gh < HH && gw >= 0 && gw < WW);
        const bool it = (sy >= PAD && sy < PAD + TH && sx >= PAD && sx < PAD + TW);
        uint4 qp = zz, vp = zz;
        if (in) {
            const long long off = (long long)b * BSTR + (long long)gh * WW + gw;
            float4 t0 = xb[off * 2], t1 = xb[off * 2 + 1];
            float xa[Cc] = {t0.x, t0.y, t0.z, t0.w, t1.x, t1.y, t1.z, t1.w};
            px_qv(xa, sw, sb, it, qp, vp);
            if (it) vh[off] = vp;
        }
        qs[s] = qp;
        if (it) vs[(sy - PAD) * TW + (sx - PAD)] = vp;
    }
    __syncthreads();

    // --- K loop (R6/R7-verified) ---
    f32x4 acc0 = (f32x4){0.f, 0.f, 0.f, 0.f};
    f32x4 acc1 = (f32x4){0.f, 0.f, 0.f, 0.f};
    const int colbase = cx + m + g;
#pragma unroll
    for (int dyp = 0; dyp < 10; ++dyp) {
        const int rb = (r0 + dyp) * QSTR + colbase;
#pragma unroll
        for (int dxb = 0; dxb < 2; ++dxb) {
            short8 qv = *(const short8*)&qs[rb + 4 * dxb];
            if (dyp < 8)
                acc0 = __builtin_amdgcn_mfma_f32_16x16x32_bf16(bw[dyp][dxb], qv, acc0, 0, 0, 0);
            if (dyp >= 2)
                acc1 = __builtin_amdgcn_mfma_f32_16x16x32_bf16(bw[dyp - 2][dxb], qv, acc1, 0, 0, 0);
        }
    }

    // --- in-register transpose ---
    float o[Cc];
#pragma unroll
    for (int tt = 0; tt < 4; ++tt) {
        float s0v = __shfl_xor(acc0[tt], 16);
        float s1v = __shfl_xor(acc1[tt], 16);
        o[tt]     = p ? s1v      : acc0[tt];
        o[4 + tt] = p ? acc1[tt] : s0v;
    }

    // --- epilogue: v from vs, softmax, write q1 ---
    uint4 vhv = vs[row * TW + px];
    float vv[Cc] = {hlo(vhv.x), hhi(vhv.x), hlo(vhv.y), hhi(vhv.y),
                    hlo(vhv.z), hhi(vhv.z), hlo(vhv.w), hhi(vhv.w)};
#pragma unroll
    for (int d = 0; d < Cc; ++d) o[d] = vv[d] - o[d];
    float mm = o[0];
#pragma unroll
    for (int d = 1; d < Cc; ++d) mm = fmaxf(mm, o[d]);
    float ss2 = 0.f, e[Cc];
#pragma unroll
    for (int d = 0; d < Cc; ++d) { e[d] = __expf(o[d] - mm); ss2 += e[d]; }
    float inv = 1.f / ss2;
    uint4 qo;
    qo.x = f2bf(e[0] * inv) | ((unsigned)f2bf(e[1] * inv) << 16);
    qo.y = f2bf(e[2] * inv) | ((unsigned)f2bf(e[3] * inv) << 16);
    qo.z = f2bf(e[4] * inv) | ((unsigned)f2bf(e[5] * inv) << 16);
    qo.w = f2bf(e[6] * inv) | ((unsigned)f2bf(e[7] * inv) << 16);
    qout[pix] = qo;
}

// ---------------------------------------------------------------------------
// mrf_iter: R7/R8-verified iteration kernel (VHALF: v fp16 vs fp32).
// ---------------------------------------------------------------------------
template<int VHALF>
__global__ __launch_bounds__(512)
void mrf_iter(const uint4* __restrict__ qin,
              const unsigned short* __restrict__ wtab,
              const void* __restrict__ vsrc,
              uint4* __restrict__ qout,
              float* __restrict__ lout,
              int last) {
    __shared__ __align__(16) uint4 qs[2][NSTG];

    const int tid = threadIdx.x;
    const int wv  = tid >> 6;
    const int l   = tid & 63;
    const int m   = l & 15;
    const int g   = l >> 4;

    const int w0 = blockIdx.x * TW;
    const int h0 = blockIdx.y * TH;
    const int b0 = blockIdx.z * NB;

    const int r0 = 4 * (wv >> 1);
    const int cx = 16 * (wv & 1);

    const int p   = g & 1;
    const int row = r0 + 2 * p + (g >> 1);
    const int px  = cx + m;
    const long long pixoff = (long long)(h0 + row) * WW + (w0 + px);
    const long long BSTR   = (long long)HH * WW;

    short8 bw[8][2];
#pragma unroll
    for (int dyq = 0; dyq < 8; ++dyq)
#pragma unroll
        for (int dxb = 0; dxb < 2; ++dxb) {
            int s = dyq * 8 + 4 * dxb + g;
            uint4 t = *(const uint4*)(wtab + (s * 16 + m) * 8);
            bw[dyq][dxb] = __builtin_bit_cast(short8, t);
        }

    const int sy0 = tid / QSTR, sx0 = tid - sy0 * QSTR;
    const int gh0 = h0 + sy0 - PAD, gw0 = w0 + sx0 - PAD;
    const bool in0 = (gh0 >= 0 && gh0 < HH && gw0 >= 0 && gw0 < WW);
    const long long off0 = (long long)gh0 * WW + gw0;
    const int  s1  = tid + 512;
    const bool has1 = (s1 < NSTG);
    const int sy1 = s1 / QSTR, sx1 = s1 - sy1 * QSTR;
    const int gh1 = h0 + sy1 - PAD, gw1 = w0 + sx1 - PAD;
    const bool in1 = has1 && (gh1 >= 0 && gh1 < HH && gw1 >= 0 && gw1 < WW);
    const long long off1 = (long long)gh1 * WW + gw1;

    const uint4* qb = qin + b0 * BSTR;
    const uint4  zz = make_uint4(0, 0, 0, 0);

    uint4 c0 = in0 ? qb[off0] : zz;
    uint4 c1 = in1 ? qb[off1] : zz;
    uint4  vhv = zz;
    float4 v0, v1;
    if constexpr (VHALF) {
        vhv = ((const uint4*)vsrc)[b0 * BSTR + pixoff];
    } else {
        const float4* vp0 = (const float4*)((const float*)vsrc + (b0 * BSTR + pixoff) * Cc);
        v0 = vp0[0]; v1 = vp0[1];
    }
    qs[0][tid] = c0;
    if (has1) qs[0][s1] = c1;
    __syncthreads();

#pragma unroll
    for (int t = 0; t < NB; ++t) {
        uint4 n0 = zz, n1 = zz, vhn = zz;
        float4 vn0 = make_float4(0.f, 0.f, 0.f, 0.f), vn1 = vn0;
        if (t + 1 < NB) {
            const uint4* qbn = qb + (t + 1) * BSTR;
            n0 = in0 ? qbn[off0] : zz;
            n1 = in1 ? qbn[off1] : zz;
            if constexpr (VHALF) {
                vhn = ((const uint4*)vsrc)[(b0 + t + 1) * BSTR + pixoff];
            } else {
                const float4* vpn = (const float4*)((const float*)vsrc + ((b0 + t + 1) * BSTR + pixoff) * Cc);
                vn0 = vpn[0]; vn1 = vpn[1];
            }
        }

        f32x4 acc0 = (f32x4){0.f, 0.f, 0.f, 0.f};
        f32x4 acc1 = (f32x4){0.f, 0.f, 0.f, 0.f};
        const uint4* Q = qs[t & 1];
        const int colbase = cx + m + g;
#pragma unroll
        for (int dyp = 0; dyp < 10; ++dyp) {
            const int rb = (r0 + dyp) * QSTR + colbase;
#pragma unroll
            for (int dxb = 0; dxb < 2; ++dxb) {
                short8 qv = *(const short8*)&Q[rb + 4 * dxb];
                if (dyp < 8)
                    acc0 = __builtin_amdgcn_mfma_f32_16x16x32_bf16(bw[dyp][dxb], qv, acc0, 0, 0, 0);
                if (dyp >= 2)
                    acc1 = __builtin_amdgcn_mfma_f32_16x16x32_bf16(bw[dyp - 2][dxb], qv, acc1, 0, 0, 0);
            }
        }

        float o[Cc];
#pragma unroll
        for (int tt = 0; tt < 4; ++tt) {
            float s0v = __shfl_xor(acc0[tt], 16);
            float s1v = __shfl_xor(acc1[tt], 16);
            o[tt]     = p ? s1v      : acc0[tt];
            o[4 + tt] = p ? acc1[tt] : s0v;
        }

        float vv[Cc];
        if constexpr (VHALF) {
            vv[0] = hlo(vhv.x); vv[1] = hhi(vhv.x);
            vv[2] = hlo(vhv.y); vv[3] = hhi(vhv.y);
            vv[4] = hlo(vhv.z); vv[5] = hhi(vhv.z);
            vv[6] = hlo(vhv.w); vv[7] = hhi(vhv.w);
        } else {
            vv[0] = v0.x; vv[1] = v0.y; vv[2] = v0.z; vv[3] = v0.w;
            vv[4] = v1.x; vv[5] = v1.y; vv[6] = v1.z; vv[7] = v1.w;
        }
#pragma unroll
        for (int d = 0; d < Cc; ++d) o[d] = vv[d] - o[d];
        const long long pix = (b0 + t) * BSTR + pixoff;
        if (last) {
            float4* op = (float4*)(lout + pix * Cc);
            op[0] = make_float4(o[0], o[1], o[2], o[3]);
            op[1] = make_float4(o[4], o[5], o[6], o[7]);
        } else {
            float mm = o[0];
#pragma unroll
            for (int d = 1; d < Cc; ++d) mm = fmaxf(mm, o[d]);
            float ss = 0.f, e[Cc];
#pragma unroll
            for (int d = 0; d < Cc; ++d) { e[d] = __expf(o[d] - mm); ss += e[d]; }
            float inv = 1.f / ss;
            uint4 qo;
            qo.x = f2bf(e[0] * inv) | ((unsigned)f2bf(e[1] * inv) << 16);
            qo.y = f2bf(e[2] * inv) | ((unsigned)f2bf(e[3] * inv) << 16);
            qo.z = f2bf(e[4] * inv) | ((unsigned)f2bf(e[5] * inv) << 16);
            qo.w = f2bf(e[6] * inv) | ((unsigned)f2bf(e[7] * inv) << 16);
            qout[pix] = qo;
        }

        if (t + 1 < NB) {
            qs[(t + 1) & 1][tid] = n0;
            if (has1) qs[(t + 1) & 1][s1] = n1;
            __syncthreads();
            if constexpr (VHALF) { vhv = vhn; } else { v0 = vn0; v1 = vn1; }
        }
    }
}

extern "C" void kernel_launch(void* const* d_in, const int* in_sizes, int n_in,
                              void* d_out, int out_size, void* d_ws, size_t ws_size,
                              hipStream_t stream) {
    (void)in_sizes; (void)n_in; (void)out_size;
    const float* x  = (const float*)d_in[0];   // [32,384,384,8]
    const float* kw = (const float*)d_in[1];   // [7,7,8,8]
    const float* sw = (const float*)d_in[2];   // [8,8]
    const float* sb = (const float*)d_in[3];   // [8]

    const size_t QSZ = (size_t)BB * HH * WW * 16;   // 75,497,472 B (bf16x8)
    const size_t VSZ = (size_t)BB * HH * WW * 16;   // 75,497,472 B (fp16x8)
    uint4* qA = (uint4*)d_ws;
    uint4* qB = (uint4*)((char*)d_ws + QSZ);

    const long long npix = (long long)BB * HH * WW;
    dim3 grid(WW / TW, HH / TH, BB / NB);   // 12 x 24 x 8

    if (ws_size >= 2 * QSZ + VSZ + 16384) {
        // fp16-v path with fused (NB=1) first iteration
        uint4* vh = (uint4*)((char*)d_ws + 2 * QSZ);
        unsigned short* wt = (unsigned short*)((char*)d_ws + 2 * QSZ + VSZ);
        prep_w<<<2, 256, 0, stream>>>(kw, sw, wt);
        dim3 gridF(WW / TW, HH / TH, BB);   // 12 x 24 x 32
        mrf_first<<<gridF, 512, 0, stream>>>(x, wt, sw, sb, vh, qB);
        mrf_iter<1><<<grid, 512, 0, stream>>>(qB, wt, vh, qA, nullptr, 0);
        mrf_iter<1><<<grid, 512, 0, stream>>>(qA, wt, vh, qB, nullptr, 0);
        mrf_iter<1><<<grid, 512, 0, stream>>>(qB, wt, vh, qA, nullptr, 0);
        mrf_iter<1><<<grid, 512, 0, stream>>>(qA, wt, vh, nullptr, (float*)d_out, 1);
    } else {
        // fallback: exact R7-verified fp32-v-in-d_out path
        float* vbuf = (float*)d_out;
        unsigned short* wt = (unsigned short*)((char*)d_ws + 2 * QSZ);
        prep_w<<<2, 256, 0, stream>>>(kw, sw, wt);
        init_qv<<<(int)(npix / 256), 256, 0, stream>>>(x, sw, sb, qA, vbuf);
        mrf_iter<0><<<grid, 512, 0, stream>>>(qA, wt, vbuf, qB, nullptr, 0);
        mrf_iter<0><<<grid, 512, 0, stream>>>(qB, wt, vbuf, qA, nullptr, 0);
        mrf_iter<0><<<grid, 512, 0, stream>>>(qA, wt, vbuf, qB, nullptr, 0);
        mrf_iter<0><<<grid, 512, 0, stream>>>(qB, wt, vbuf, qA, nullptr, 0);
        mrf_iter<0><<<grid, 512, 0, stream>>>(qA, wt, vbuf, nullptr, (float*)d_out, 1);
    }
}

// Round 11
// 361.514 us; speedup vs baseline: 1.0725x; 1.0556x over previous
//
#include <hip/hip_runtime.h>
#include <math.h>

#define Cc     8
#define FIELD  7
#define PAD    3
#define TW     32        // tile width
#define TH     16        // tile height
#define HAW    38        // TW + 6
#define HAH    22        // TH + 6
#define QSTR   39        // qs row stride (uint4); col 38 = pad col (staged, zero weight)
#define NSTG   (HAH*QSTR)  // 858 staged uint4 per tile
#define BB     32
#define HH     384
#define WW     384
#define NB     4         // batches per block (software-pipelined)
#define NSLOT  64        // 8 dy' x 8 dx slots (dx==7 zero-pad) for a row-PAIR
#define UCLIP  13.815510557964274f   // -log(1e-6)

typedef __attribute__((ext_vector_type(8))) short short8;  // 8 bf16 = 4 VGPRs
typedef __attribute__((ext_vector_type(4))) float f32x4;   // MFMA C/D

__device__ __forceinline__ unsigned short f2bf(float f) {   // RNE fp32->bf16
    unsigned u = __float_as_uint(f);
    u += 0x7FFFu + ((u >> 16) & 1u);
    return (unsigned short)(u >> 16);
}
__device__ __forceinline__ unsigned short f2h(float f) {    // RNE fp32->fp16
    return __builtin_bit_cast(unsigned short, (_Float16)f);
}
__device__ __forceinline__ float hlo(unsigned u) {
    return (float)__builtin_bit_cast(_Float16, (unsigned short)(u & 0xFFFFu));
}
__device__ __forceinline__ float hhi(unsigned u) {
    return (float)__builtin_bit_cast(_Float16, (unsigned short)(u >> 16));
}

// ---------------------------------------------------------------------------
// prep_w: row-pair fused weight table, dx-major slot layout (R6/R7-verified).
// Slot s = dy'*8 + dx, dy' in [0,8), dx in [0,8) (dx==7 -> zero column).
// For n = 8h + d: wtab[s][n][j] = W[(dy'-h)*7+dx][j][d] if 0<=dy'-h<7 && dx<7
// else 0, W[tap][j][d] = sum_c kw[tap][j][c]*(c!=j)*sw[c][d].
// ---------------------------------------------------------------------------
__global__ __launch_bounds__(256)
void prep_w(const float* __restrict__ kw, const float* __restrict__ sw,
            unsigned short* __restrict__ wtab) {
    int it = blockIdx.x * 256 + threadIdx.x;      // (slot, j=cin)
    if (it >= NSLOT * 8) return;
    int s = it >> 3, j = it & 7;
    int dyp = s >> 3, dx = s & 7;
#pragma unroll
    for (int n = 0; n < 16; ++n) {
        int h = n >> 3, d = n & 7;
        int dy = dyp - h;
        float a = 0.f;
        if (dy >= 0 && dy < FIELD && dx < 7) {
            int tap = dy * 7 + dx;
#pragma unroll
            for (int c = 0; c < Cc; ++c) {
                float kv = (c == j) ? 0.f : kw[(tap * Cc + j) * Cc + c];
                a = fmaf(kv, sw[c * Cc + d], a);
            }
        }
        wtab[(s * 16 + n) * 8 + j] = f2bf(a);
    }
}

// ---------------------------------------------------------------------------
// init_qv: q0 = softmax(x) bf16x8; v = b - u@W (u = min(lse-x, UCLIP)).
// 2 pixels per thread (p and p+npix/2) -> two independent dependency chains
// (ILP over the 10-transcendental softmax/v chain), all loads/stores remain
// per-instruction coalesced. Math per pixel identical to R8 (absmax-stable).
// v stored fp16 (vh) when half!=0, else fp32 (vf).
// ---------------------------------------------------------------------------
__global__ __launch_bounds__(256)
void init_qv(const float* __restrict__ x, const float* __restrict__ sw,
             const float* __restrict__ sb,
             uint4* __restrict__ q0, float* __restrict__ vf,
             uint4* __restrict__ vh, int half) {
    const long long HALF = (long long)BB * HH * WW / 2;
    const long long p0 = (long long)blockIdx.x * 256 + threadIdx.x;
    const long long p1 = p0 + HALF;

    const float4* xp0 = (const float4*)(x + p0 * Cc);
    const float4* xp1 = (const float4*)(x + p1 * Cc);
    float4 a0 = xp0[0], a1 = xp0[1];     // issue all 4 loads up front
    float4 b0 = xp1[0], b1 = xp1[1];

    float xa[Cc] = {a0.x, a0.y, a0.z, a0.w, a1.x, a1.y, a1.z, a1.w};
    float xb[Cc] = {b0.x, b0.y, b0.z, b0.w, b1.x, b1.y, b1.z, b1.w};

    float ma = xa[0], mb = xb[0];
#pragma unroll
    for (int c = 1; c < Cc; ++c) { ma = fmaxf(ma, xa[c]); mb = fmaxf(mb, xb[c]); }
    float sa = 0.f, sb_ = 0.f, ea[Cc], eb[Cc];
#pragma unroll
    for (int c = 0; c < Cc; ++c) {
        ea[c] = __expf(xa[c] - ma); sa += ea[c];
        eb[c] = __expf(xb[c] - mb); sb_ += eb[c];
    }
    float ia = 1.f / sa, ib = 1.f / sb_;
    uint4 qa, qb;
    qa.x = f2bf(ea[0] * ia) | ((unsigned)f2bf(ea[1] * ia) << 16);
    qa.y = f2bf(ea[2] * ia) | ((unsigned)f2bf(ea[3] * ia) << 16);
    qa.z = f2bf(ea[4] * ia) | ((unsigned)f2bf(ea[5] * ia) << 16);
    qa.w = f2bf(ea[6] * ia) | ((unsigned)f2bf(ea[7] * ia) << 16);
    qb.x = f2bf(eb[0] * ib) | ((unsigned)f2bf(eb[1] * ib) << 16);
    qb.y = f2bf(eb[2] * ib) | ((unsigned)f2bf(eb[3] * ib) << 16);
    qb.z = f2bf(eb[4] * ib) | ((unsigned)f2bf(eb[5] * ib) << 16);
    qb.w = f2bf(eb[6] * ib) | ((unsigned)f2bf(eb[7] * ib) << 16);
    q0[p0] = qa;
    q0[p1] = qb;

    float lsea = ma + __logf(sa), lseb = mb + __logf(sb_);
    float ua[Cc], ub[Cc];
#pragma unroll
    for (int c = 0; c < Cc; ++c) {
        ua[c] = fminf(lsea - xa[c], UCLIP);
        ub[c] = fminf(lseb - xb[c], UCLIP);
    }
    float va[Cc], vb[Cc];
#pragma unroll
    for (int d = 0; d < Cc; ++d) {
        float aa = sb[d], ab = sb[d];
#pragma unroll
        for (int c = 0; c < Cc; ++c) {
            float w = sw[c * Cc + d];
            aa = fmaf(-ua[c], w, aa);
            ab = fmaf(-ub[c], w, ab);
        }
        va[d] = aa; vb[d] = ab;
    }
    if (half) {
        uint4 voa, vob;
        voa.x = f2h(va[0]) | ((unsigned)f2h(va[1]) << 16);
        voa.y = f2h(va[2]) | ((unsigned)f2h(va[3]) << 16);
        voa.z = f2h(va[4]) | ((unsigned)f2h(va[5]) << 16);
        voa.w = f2h(va[6]) | ((unsigned)f2h(va[7]) << 16);
        vob.x = f2h(vb[0]) | ((unsigned)f2h(vb[1]) << 16);
        vob.y = f2h(vb[2]) | ((unsigned)f2h(vb[3]) << 16);
        vob.z = f2h(vb[4]) | ((unsigned)f2h(vb[5]) << 16);
        vob.w = f2h(vb[6]) | ((unsigned)f2h(vb[7]) << 16);
        vh[p0] = voa;
        vh[p1] = vob;
    } else {
        float4* vpa = (float4*)(vf + p0 * Cc);
        vpa[0] = make_float4(va[0], va[1], va[2], va[3]);
        vpa[1] = make_float4(va[4], va[5], va[6], va[7]);
        float4* vpb = (float4*)(vf + p1 * Cc);
        vpb[0] = make_float4(vb[0], vb[1], vb[2], vb[3]);
        vpb[1] = make_float4(vb[4], vb[5], vb[6], vb[7]);
    }
}

// ---------------------------------------------------------------------------
// mrf_iter: R7/R8-verified iteration kernel (VHALF: v fp16 vs fp32).
// ---------------------------------------------------------------------------
template<int VHALF>
__global__ __launch_bounds__(512)
void mrf_iter(const uint4* __restrict__ qin,
              const unsigned short* __restrict__ wtab,
              const void* __restrict__ vsrc,
              uint4* __restrict__ qout,
              float* __restrict__ lout,
              int last) {
    __shared__ __align__(16) uint4 qs[2][NSTG];

    const int tid = threadIdx.x;
    const int wv  = tid >> 6;
    const int l   = tid & 63;
    const int m   = l & 15;
    const int g   = l >> 4;

    const int w0 = blockIdx.x * TW;
    const int h0 = blockIdx.y * TH;
    const int b0 = blockIdx.z * NB;

    const int r0 = 4 * (wv >> 1);
    const int cx = 16 * (wv & 1);

    const int p   = g & 1;
    const int row = r0 + 2 * p + (g >> 1);
    const int px  = cx + m;
    const long long pixoff = (long long)(h0 + row) * WW + (w0 + px);
    const long long BSTR   = (long long)HH * WW;

    short8 bw[8][2];
#pragma unroll
    for (int dyq = 0; dyq < 8; ++dyq)
#pragma unroll
        for (int dxb = 0; dxb < 2; ++dxb) {
            int s = dyq * 8 + 4 * dxb + g;
            uint4 t = *(const uint4*)(wtab + (s * 16 + m) * 8);
            bw[dyq][dxb] = __builtin_bit_cast(short8, t);
        }

    const int sy0 = tid / QSTR, sx0 = tid - sy0 * QSTR;
    const int gh0 = h0 + sy0 - PAD, gw0 = w0 + sx0 - PAD;
    const bool in0 = (gh0 >= 0 && gh0 < HH && gw0 >= 0 && gw0 < WW);
    const long long off0 = (long long)gh0 * WW + gw0;
    const int  s1  = tid + 512;
    const bool has1 = (s1 < NSTG);
    const int sy1 = s1 / QSTR, sx1 = s1 - sy1 * QSTR;
    const int gh1 = h0 + sy1 - PAD, gw1 = w0 + sx1 - PAD;
    const bool in1 = has1 && (gh1 >= 0 && gh1 < HH && gw1 >= 0 && gw1 < WW);
    const long long off1 = (long long)gh1 * WW + gw1;

    const uint4* qb = qin + b0 * BSTR;
    const uint4  zz = make_uint4(0, 0, 0, 0);

    uint4 c0 = in0 ? qb[off0] : zz;
    uint4 c1 = in1 ? qb[off1] : zz;
    uint4  vhv = zz;
    float4 v0, v1;
    if constexpr (VHALF) {
        vhv = ((const uint4*)vsrc)[b0 * BSTR + pixoff];
    } else {
        const float4* vp0 = (const float4*)((const float*)vsrc + (b0 * BSTR + pixoff) * Cc);
        v0 = vp0[0]; v1 = vp0[1];
    }
    qs[0][tid] = c0;
    if (has1) qs[0][s1] = c1;
    __syncthreads();

#pragma unroll
    for (int t = 0; t < NB; ++t) {
        uint4 n0 = zz, n1 = zz, vhn = zz;
        float4 vn0 = make_float4(0.f, 0.f, 0.f, 0.f), vn1 = vn0;
        if (t + 1 < NB) {
            const uint4* qbn = qb + (t + 1) * BSTR;
            n0 = in0 ? qbn[off0] : zz;
            n1 = in1 ? qbn[off1] : zz;
            if constexpr (VHALF) {
                vhn = ((const uint4*)vsrc)[(b0 + t + 1) * BSTR + pixoff];
            } else {
                const float4* vpn = (const float4*)((const float*)vsrc + ((b0 + t + 1) * BSTR + pixoff) * Cc);
                vn0 = vpn[0]; vn1 = vpn[1];
            }
        }

        f32x4 acc0 = (f32x4){0.f, 0.f, 0.f, 0.f};
        f32x4 acc1 = (f32x4){0.f, 0.f, 0.f, 0.f};
        const uint4* Q = qs[t & 1];
        const int colbase = cx + m + g;
#pragma unroll
        for (int dyp = 0; dyp < 10; ++dyp) {
            const int rb = (r0 + dyp) * QSTR + colbase;
#pragma unroll
            for (int dxb = 0; dxb < 2; ++dxb) {
                short8 qv = *(const short8*)&Q[rb + 4 * dxb];
                if (dyp < 8)
                    acc0 = __builtin_amdgcn_mfma_f32_16x16x32_bf16(bw[dyp][dxb], qv, acc0, 0, 0, 0);
                if (dyp >= 2)
                    acc1 = __builtin_amdgcn_mfma_f32_16x16x32_bf16(bw[dyp - 2][dxb], qv, acc1, 0, 0, 0);
            }
        }

        float o[Cc];
#pragma unroll
        for (int tt = 0; tt < 4; ++tt) {
            float s0v = __shfl_xor(acc0[tt], 16);
            float s1v = __shfl_xor(acc1[tt], 16);
            o[tt]     = p ? s1v      : acc0[tt];
            o[4 + tt] = p ? acc1[tt] : s0v;
        }

        float vv[Cc];
        if constexpr (VHALF) {
            vv[0] = hlo(vhv.x); vv[1] = hhi(vhv.x);
            vv[2] = hlo(vhv.y); vv[3] = hhi(vhv.y);
            vv[4] = hlo(vhv.z); vv[5] = hhi(vhv.z);
            vv[6] = hlo(vhv.w); vv[7] = hhi(vhv.w);
        } else {
            vv[0] = v0.x; vv[1] = v0.y; vv[2] = v0.z; vv[3] = v0.w;
            vv[4] = v1.x; vv[5] = v1.y; vv[6] = v1.z; vv[7] = v1.w;
        }
#pragma unroll
        for (int d = 0; d < Cc; ++d) o[d] = vv[d] - o[d];
        const long long pix = (b0 + t) * BSTR + pixoff;
        if (last) {
            float4* op = (float4*)(lout + pix * Cc);
            op[0] = make_float4(o[0], o[1], o[2], o[3]);
            op[1] = make_float4(o[4], o[5], o[6], o[7]);
        } else {
            float mm = o[0];
#pragma unroll
            for (int d = 1; d < Cc; ++d) mm = fmaxf(mm, o[d]);
            float ss = 0.f, e[Cc];
#pragma unroll
            for (int d = 0; d < Cc; ++d) { e[d] = __expf(o[d] - mm); ss += e[d]; }
            float inv = 1.f / ss;
            uint4 qo;
            qo.x = f2bf(e[0] * inv) | ((unsigned)f2bf(e[1] * inv) << 16);
            qo.y = f2bf(e[2] * inv) | ((unsigned)f2bf(e[3] * inv) << 16);
            qo.z = f2bf(e[4] * inv) | ((unsigned)f2bf(e[5] * inv) << 16);
            qo.w = f2bf(e[6] * inv) | ((unsigned)f2bf(e[7] * inv) << 16);
            qout[pix] = qo;
        }

        if (t + 1 < NB) {
            qs[(t + 1) & 1][tid] = n0;
            if (has1) qs[(t + 1) & 1][s1] = n1;
            __syncthreads();
            if constexpr (VHALF) { vhv = vhn; } else { v0 = vn0; v1 = vn1; }
        }
    }
}

extern "C" void kernel_launch(void* const* d_in, const int* in_sizes, int n_in,
                              void* d_out, int out_size, void* d_ws, size_t ws_size,
                              hipStream_t stream) {
    (void)in_sizes; (void)n_in; (void)out_size;
    const float* x  = (const float*)d_in[0];   // [32,384,384,8]
    const float* kw = (const float*)d_in[1];   // [7,7,8,8]
    const float* sw = (const float*)d_in[2];   // [8,8]
    const float* sb = (const float*)d_in[3];   // [8]

    const size_t QSZ = (size_t)BB * HH * WW * 16;   // 75,497,472 B (bf16x8)
    const size_t VSZ = (size_t)BB * HH * WW * 16;   // 75,497,472 B (fp16x8)
    uint4* qA = (uint4*)d_ws;
    uint4* qB = (uint4*)((char*)d_ws + QSZ);

    const long long npix = (long long)BB * HH * WW;
    dim3 grid(WW / TW, HH / TH, BB / NB);   // 12 x 24 x 8

    if (ws_size >= 2 * QSZ + VSZ + 16384) {
        // fp16-v path: whole iteration working set {qA,qB,v} = 226.5 MB < L3
        uint4* vh = (uint4*)((char*)d_ws + 2 * QSZ);
        unsigned short* wt = (unsigned short*)((char*)d_ws + 2 * QSZ + VSZ);
        prep_w<<<2, 256, 0, stream>>>(kw, sw, wt);
        init_qv<<<(int)(npix / 512), 256, 0, stream>>>(x, sw, sb, qA, nullptr, vh, 1);
        mrf_iter<1><<<grid, 512, 0, stream>>>(qA, wt, vh, qB, nullptr, 0);
        mrf_iter<1><<<grid, 512, 0, stream>>>(qB, wt, vh, qA, nullptr, 0);
        mrf_iter<1><<<grid, 512, 0, stream>>>(qA, wt, vh, qB, nullptr, 0);
        mrf_iter<1><<<grid, 512, 0, stream>>>(qB, wt, vh, qA, nullptr, 0);
        mrf_iter<1><<<grid, 512, 0, stream>>>(qA, wt, vh, nullptr, (float*)d_out, 1);
    } else {
        // fallback: exact R7-verified fp32-v-in-d_out path
        float* vbuf = (float*)d_out;
        unsigned short* wt = (unsigned short*)((char*)d_ws + 2 * QSZ);
        prep_w<<<2, 256, 0, stream>>>(kw, sw, wt);
        init_qv<<<(int)(npix / 512), 256, 0, stream>>>(x, sw, sb, qA, vbuf, nullptr, 0);
        mrf_iter<0><<<grid, 512, 0, stream>>>(qA, wt, vbuf, qB, nullptr, 0);
        mrf_iter<0><<<grid, 512, 0, stream>>>(qB, wt, vbuf, qA, nullptr, 0);
        mrf_iter<0><<<grid, 512, 0, stream>>>(qA, wt, vbuf, qB, nullptr, 0);
        mrf_iter<0><<<grid, 512, 0, stream>>>(qB, wt, vbuf, qA, nullptr, 0);
        mrf_iter<0><<<grid, 512, 0, stream>>>(qA, wt, vbuf, nullptr, (float*)d_out, 1);
    }
}